// Round 5
// baseline (740.933 us; speedup 1.0000x reference)
//
#include <hip/hip_runtime.h>

#define N_ROWS 4096
#define D_DIM  512
#define C_CLS  100000
#define S_SCALE 30.0f
#define MARGIN  0.4f

#define KS 16            // k-steps of 32 over D=512
#define NT 4             // n-tiles (16 rows each) per wave
#define MTMAX 5          // max m-tiles (16 classes) per block
#define NBLK 1536        // 6250 = 1536*4 + 106; 3 exact rounds of 512 resident blocks
#define BASE_MT 4
#define EXTRA_T 106
#define LDS_BYTES (MTMAX * KS * 64 * 16)   // 81920 B = 80 KiB -> 2 blocks/CU
#define RS_SLICES 64     // row_sum slices: cuts per-address atomic contention 64x

// S_SCALE * log2(e): folded into the packed xn so epilogue is a bare exp2
#define S_LOG2E 43.2808512266689f

typedef __attribute__((ext_vector_type(8))) __bf16 bf16x8;
typedef __attribute__((ext_vector_type(4))) float floatx4;

__device__ inline unsigned int f2bf_rne(float f) {
    unsigned int u = __builtin_bit_cast(unsigned int, f);
    u += 0x7fffu + ((u >> 16) & 1u);
    return u >> 16;
}

__device__ inline uint4 pack_bf16x8(float4 a, float4 b) {
    uint4 r;
    r.x = f2bf_rne(a.x) | (f2bf_rne(a.y) << 16);
    r.y = f2bf_rne(a.z) | (f2bf_rne(a.w) << 16);
    r.z = f2bf_rne(b.x) | (f2bf_rne(b.y) << 16);
    r.w = f2bf_rne(b.z) | (f2bf_rne(b.w) << 16);
    return r;
}

__device__ __forceinline__ floatx4 mfma16(uint4 a, uint4 b, floatx4 c) {
    return __builtin_amdgcn_mfma_f32_16x16x32_bf16(
        __builtin_bit_cast(bf16x8, a), __builtin_bit_cast(bf16x8, b), c, 0, 0, 0);
}

// ---- Phase 1: row-normalize x, pack bf16 B-fragments scaled by s*log2(e),
//      fp32 target logit (unscaled), zero the sliced row_sum
__global__ __launch_bounds__(256) void normalize_pack(
    const float* __restrict__ x, const int* __restrict__ labels,
    const float* __restrict__ W, uint4* __restrict__ xnp, float* __restrict__ target,
    float* __restrict__ row_sum)
{
    // grid is 1024*256 = 262144 threads = RS_SLICES * N_ROWS exactly
    const int gt = blockIdx.x * 256 + threadIdx.x;
    row_sum[gt] = 0.f;

    const int lane = threadIdx.x & 63;
    const int r = blockIdx.x * 4 + (threadIdx.x >> 6);   // one wave per row
    const float4* xr = (const float4*)(x + (size_t)r * D_DIM);
    float4 a = xr[lane * 2], b = xr[lane * 2 + 1];
    float ss = a.x*a.x + a.y*a.y + a.z*a.z + a.w*a.w
             + b.x*b.x + b.y*b.y + b.z*b.z + b.w*b.w;
    #pragma unroll
    for (int o = 1; o < 64; o <<= 1) ss += __shfl_xor(ss, o, 64);
    const float inv = 1.0f / sqrtf(ss);

    const int lab = labels[r];
    const float4* wr = (const float4*)(W + (size_t)lab * D_DIM);
    float4 wa = wr[lane * 2], wb = wr[lane * 2 + 1];
    float dot = a.x*wa.x + a.y*wa.y + a.z*wa.z + a.w*wa.w
              + b.x*wb.x + b.y*wb.y + b.z*wb.z + b.w*wb.w;
    #pragma unroll
    for (int o = 1; o < 64; o <<= 1) dot += __shfl_xor(dot, o, 64);
    if (lane == 0) target[r] = dot * inv;          // exact fp32 target logit

    const float invs = inv * S_LOG2E;              // fold s*log2e into bf16 pack
    float4 na = {a.x*invs, a.y*invs, a.z*invs, a.w*invs};
    float4 nb = {b.x*invs, b.y*invs, b.z*invs, b.w*invs};
    // B-fragment packing: lane holds B[n=lane&15][k=(lane>>4)*8 + j]
    const int nt = r >> 4, ks = lane >> 2, li = (r & 15) | ((lane & 3) << 4);
    xnp[(size_t)(nt * KS + ks) * 64 + li] = pack_bf16x8(na, nb);
}

// ---- Phase 2 inner loop, specialized per stripe width (4 or 5 m-tiles) ----
// B-fragments (global/L2) explicitly double-buffered: the k+1 loads issue
// BEFORE the k MFMA cluster, guaranteeing >= 1 MFMA-set (~400-800 cyc) of
// latency cover for L2-miss->IC round trips. setprio(1) keeps the matrix
// pipe preferred while co-resident waves issue their loads (T5: barrier-free
// structure = wave role diversity = setprio's paying regime).
template<int CNT>
__device__ __forceinline__ void run_stripe(
    const uint4* __restrict__ xnp, const uint4* __restrict__ sW,
    float* __restrict__ rs, int w, int lane)
{
    for (int iter = 0; iter < N_ROWS / 512; ++iter) {   // 8 iters, wave covers 64 rows
        const int rbase = iter * 512 + w * 64;
        floatx4 acc[CNT][NT] = {};
        const int b0 = (rbase >> 4) * (KS * 64) + lane; // uint4 index, 32-bit

        uint4 bA[NT], bB[NT];
        #pragma unroll
        for (int nt = 0; nt < NT; ++nt)                 // prologue: B for ks=0
            bA[nt] = xnp[b0 + nt * (KS * 64)];

        #pragma unroll
        for (int ks = 0; ks < KS; ks += 2) {
            // prefetch B for ks+1 (consumed by the second half-step)
            #pragma unroll
            for (int nt = 0; nt < NT; ++nt)
                bB[nt] = xnp[b0 + nt * (KS * 64) + (ks + 1) * 64];
            uint4 afr[CNT];
            #pragma unroll
            for (int mt = 0; mt < CNT; ++mt)
                afr[mt] = sW[(mt * KS + ks) * 64 + lane];
            __builtin_amdgcn_s_setprio(1);
            #pragma unroll
            for (int mt = 0; mt < CNT; ++mt)
                #pragma unroll
                for (int nt = 0; nt < NT; ++nt)
                    acc[mt][nt] = mfma16(afr[mt], bA[nt], acc[mt][nt]);
            __builtin_amdgcn_s_setprio(0);

            // prefetch B for ks+2 (wraps harmlessly to 0 on the last body)
            const int k2 = (ks + 2) & (KS - 1);
            #pragma unroll
            for (int nt = 0; nt < NT; ++nt)
                bA[nt] = xnp[b0 + nt * (KS * 64) + k2 * 64];
            uint4 afr2[CNT];
            #pragma unroll
            for (int mt = 0; mt < CNT; ++mt)
                afr2[mt] = sW[(mt * KS + ks + 1) * 64 + lane];
            __builtin_amdgcn_s_setprio(1);
            #pragma unroll
            for (int mt = 0; mt < CNT; ++mt)
                #pragma unroll
                for (int nt = 0; nt < NT; ++nt)
                    acc[mt][nt] = mfma16(afr2[mt], bB[nt], acc[mt][nt]);
            __builtin_amdgcn_s_setprio(0);
        }

        // Epilogue: acc already holds s*log2e*logit; no tail mask (6250*16 == 100000).
        // C/D layout: n(col)=lane&15 (sample), m(row)=(lane>>4)*4+reg (class).
        float rp[NT] = {0.f, 0.f, 0.f, 0.f};
        #pragma unroll
        for (int mt = 0; mt < CNT; ++mt)
            #pragma unroll
            for (int nt = 0; nt < NT; ++nt)
                #pragma unroll
                for (int r = 0; r < 4; ++r)
                    rp[nt] += __builtin_amdgcn_exp2f(acc[mt][nt][r]);
        #pragma unroll
        for (int nt = 0; nt < NT; ++nt) {
            float v = rp[nt];
            v += __shfl_xor(v, 16, 64);
            v += __shfl_xor(v, 32, 64);
            if (lane < 16) atomicAdd(&rs[rbase + nt * 16 + lane], v);
        }
    }
}

// ---- Phase 2: variable-width stripe GEMM + fused exp-reduction ----
// 80 KiB LDS + <=128 arch-VGPR/wave -> 2 blocks/CU; atomic target sliced by
// (bid & 63) so same-line atomics stop clogging the in-order vmcnt queue.
__global__ __launch_bounds__(512, 4) void adms_main(
    const float* __restrict__ W, const uint4* __restrict__ xnp, float* __restrict__ row_sum)
{
    extern __shared__ uint4 sW[];    // 64-80 KiB, A-fragment-packed W stripe (bf16)
    const int tid = threadIdx.x, bid = blockIdx.x;
    const int tbase = bid * BASE_MT + (bid < EXTRA_T ? bid : EXTRA_T);
    const int cnt   = BASE_MT + (bid < EXTRA_T ? 1 : 0);   // m-tiles this block: 4 or 5
    const int c0 = tbase * 16;

    // Stage W stripe fp32->bf16 into LDS in A-fragment order (no OOB possible).
    for (int g = tid >> 6; g < cnt * KS; g += 8) {
        const int mt = g >> 4, ks = g & 15;
        const int j8 = tid & 3, lm = (tid >> 2) & 15;
        const int gc = c0 + mt * 16 + lm;
        const int k0 = ks * 32 + j8 * 8;
        const float4* src = (const float4*)(W + (size_t)gc * D_DIM + k0);
        sW[(mt * KS + ks) * 64 + (lm | (j8 << 4))] = pack_bf16x8(src[0], src[1]);
    }
    __syncthreads();

    const int w = tid >> 6, lane = tid & 63;
    float* rs = row_sum + (size_t)(bid & (RS_SLICES - 1)) * N_ROWS;
    if (cnt == 5) run_stripe<5>(xnp, sW, rs, w, lane);
    else          run_stripe<4>(xnp, sW, rs, w, lane);
}

// ---- Phase 3: per-row loss (summing the 64 row_sum slices) + mean ----
__global__ __launch_bounds__(1024) void finalize(
    const float* __restrict__ target, const float* __restrict__ row_sum,
    float* __restrict__ out)
{
    __shared__ float red[1024];
    const int t = threadIdx.x;
    float accum = 0.f;
    for (int r = t; r < N_ROWS; r += 1024) {
        float excl_sum = 0.f;
        #pragma unroll 8
        for (int s = 0; s < RS_SLICES; ++s)
            excl_sum += row_sum[s * N_ROWS + r];       // coalesced across t
        const float tg   = target[r];
        const float num  = S_SCALE * (tg - MARGIN);
        const float excl = excl_sum - expf(S_SCALE * tg);
        const float den  = expf(num) + excl;
        accum += num - logf(den);
    }
    red[t] = accum;
    __syncthreads();
    for (int s = 512; s > 0; s >>= 1) {
        if (t < s) red[t] += red[t + s];
        __syncthreads();
    }
    if (t == 0) out[0] = -red[0] / (float)N_ROWS;
}

extern "C" void kernel_launch(void* const* d_in, const int* in_sizes, int n_in,
                              void* d_out, int out_size, void* d_ws, size_t ws_size,
                              hipStream_t stream) {
    const float* x      = (const float*)d_in[0];
    const int*   labels = (const int*)d_in[1];
    const float* W      = (const float*)d_in[2];
    float* out = (float*)d_out;

    char* ws = (char*)d_ws;
    uint4* xnp     = (uint4*)ws;                                   // 4 MiB packed xn
    float* target  = (float*)(ws + (4u << 20));                    // 16 KiB
    float* row_sum = (float*)(ws + (4u << 20) + (16u << 10));      // 64 slices = 1 MiB

    hipFuncSetAttribute((const void*)adms_main,
                        hipFuncAttributeMaxDynamicSharedMemorySize, LDS_BYTES);

    normalize_pack<<<N_ROWS / 4, 256, 0, stream>>>(x, labels, W, xnp, target, row_sum);
    adms_main<<<NBLK, 512, LDS_BYTES, stream>>>(W, xnp, row_sum);
    finalize<<<1, 1024, 0, stream>>>(target, row_sum, out);
}

// Round 6
// 603.499 us; speedup vs baseline: 1.2277x; 1.2277x over previous
//
#include <hip/hip_runtime.h>

#define N_ROWS 4096
#define D_DIM  512
#define C_CLS  100000
#define S_SCALE 30.0f
#define MARGIN  0.4f

#define KS 16            // k-steps of 32 over D=512
#define NT 4             // n-tiles (16 rows each) per wave
#define NTG 256          // total n-tiles (4096/16)
#define MTMAX 5          // max m-tiles (16 classes) per block
#define NBLK 1536        // 6250 = 1536*4 + 106; 3 exact rounds of 512 resident blocks
#define BASE_MT 4
#define EXTRA_T 106
#define LDS_BYTES (MTMAX * KS * 64 * 16)   // 81920 B = 80 KiB -> 2 blocks/CU
#define RS_SLICES 64     // row_sum slices: cuts per-address atomic contention 64x

// S_SCALE * log2(e): folded into the packed xn so epilogue is a bare exp2
#define S_LOG2E 43.2808512266689f

typedef __attribute__((ext_vector_type(8))) __bf16 bf16x8;
typedef __attribute__((ext_vector_type(4))) float floatx4;

__device__ inline unsigned int f2bf_rne(float f) {
    unsigned int u = __builtin_bit_cast(unsigned int, f);
    u += 0x7fffu + ((u >> 16) & 1u);
    return u >> 16;
}

__device__ inline uint4 pack_bf16x8(float4 a, float4 b) {
    uint4 r;
    r.x = f2bf_rne(a.x) | (f2bf_rne(a.y) << 16);
    r.y = f2bf_rne(a.z) | (f2bf_rne(a.w) << 16);
    r.z = f2bf_rne(b.x) | (f2bf_rne(b.y) << 16);
    r.w = f2bf_rne(b.z) | (f2bf_rne(b.w) << 16);
    return r;
}

__device__ __forceinline__ floatx4 mfma16(uint4 a, uint4 b, floatx4 c) {
    return __builtin_amdgcn_mfma_f32_16x16x32_bf16(
        __builtin_bit_cast(bf16x8, a), __builtin_bit_cast(bf16x8, b), c, 0, 0, 0);
}

// ---- Phase 1: row-normalize x, pack bf16 B-fragments scaled by s*log2(e),
//      fp32 target logit (unscaled), zero the sliced row_sum.
//      xnp layout: [ks][ntg][64] so phase 2's 4 per-k-step loads are CONTIGUOUS
//      (imm offsets 0/1024/2048/3072 off one pointer, one bump per k-step).
__global__ __launch_bounds__(256) void normalize_pack(
    const float* __restrict__ x, const int* __restrict__ labels,
    const float* __restrict__ W, uint4* __restrict__ xnp, float* __restrict__ target,
    float* __restrict__ row_sum)
{
    // grid is 1024*256 = 262144 threads = RS_SLICES * N_ROWS exactly
    const int gt = blockIdx.x * 256 + threadIdx.x;
    row_sum[gt] = 0.f;

    const int lane = threadIdx.x & 63;
    const int r = blockIdx.x * 4 + (threadIdx.x >> 6);   // one wave per row
    const float4* xr = (const float4*)(x + (size_t)r * D_DIM);
    float4 a = xr[lane * 2], b = xr[lane * 2 + 1];
    float ss = a.x*a.x + a.y*a.y + a.z*a.z + a.w*a.w
             + b.x*b.x + b.y*b.y + b.z*b.z + b.w*b.w;
    #pragma unroll
    for (int o = 1; o < 64; o <<= 1) ss += __shfl_xor(ss, o, 64);
    const float inv = 1.0f / sqrtf(ss);

    const int lab = labels[r];
    const float4* wr = (const float4*)(W + (size_t)lab * D_DIM);
    float4 wa = wr[lane * 2], wb = wr[lane * 2 + 1];
    float dot = a.x*wa.x + a.y*wa.y + a.z*wa.z + a.w*wa.w
              + b.x*wb.x + b.y*wb.y + b.z*wb.z + b.w*wb.w;
    #pragma unroll
    for (int o = 1; o < 64; o <<= 1) dot += __shfl_xor(dot, o, 64);
    if (lane == 0) target[r] = dot * inv;          // exact fp32 target logit

    const float invs = inv * S_LOG2E;              // fold s*log2e into bf16 pack
    float4 na = {a.x*invs, a.y*invs, a.z*invs, a.w*invs};
    float4 nb = {b.x*invs, b.y*invs, b.z*invs, b.w*invs};
    // B-fragment packing: lane holds B[n=lane&15][k=(lane>>4)*8 + j]
    const int ntg = r >> 4, ks = lane >> 2, li = (r & 15) | ((lane & 3) << 4);
    xnp[((size_t)ks * NTG + ntg) * 64 + li] = pack_bf16x8(na, nb);
}

// ---- Phase 2 inner loop, specialized per stripe width (4 or 5 m-tiles) ----
// R5 lesson: NO full-unroll double-buffer (spilled -> 750 MB scratch traffic).
// Instead: [ks][ntg][64] xnp layout gives one pointer bump + imm-offset loads
// per k-step (cuts k-loop address VALU ~4x). setprio(1) keeps the matrix pipe
// preferred in this barrier-free multi-wave regime (T5).
template<int CNT>
__device__ __forceinline__ void run_stripe(
    const uint4* __restrict__ xnp, const uint4* __restrict__ sW,
    float* __restrict__ rs, int w, int lane)
{
    for (int iter = 0; iter < N_ROWS / 512; ++iter) {   // 8 iters, wave covers 64 rows
        const int rbase = iter * 512 + w * 64;
        floatx4 acc[CNT][NT] = {};
        // 4 consecutive n-tile fragments: bp[0],bp[64],bp[128],bp[192] (1 KiB apart)
        const uint4* bp = xnp + (size_t)(rbase >> 4) * 64 + lane;

        #pragma unroll 2
        for (int ks = 0; ks < KS; ++ks) {
            uint4 bfr[NT], afr[CNT];
            #pragma unroll
            for (int nt = 0; nt < NT; ++nt)
                bfr[nt] = bp[nt * 64];
            #pragma unroll
            for (int mt = 0; mt < CNT; ++mt)
                afr[mt] = sW[(mt * KS + ks) * 64 + lane];
            __builtin_amdgcn_s_setprio(1);
            #pragma unroll
            for (int mt = 0; mt < CNT; ++mt)
                #pragma unroll
                for (int nt = 0; nt < NT; ++nt)
                    acc[mt][nt] = mfma16(afr[mt], bfr[nt], acc[mt][nt]);
            __builtin_amdgcn_s_setprio(0);
            bp += NTG * 64;                          // next k-step: +256 KiB
        }

        // Epilogue: acc already holds s*log2e*logit; no tail mask (6250*16 == 100000).
        // C/D layout: n(col)=lane&15 (sample), m(row)=(lane>>4)*4+reg (class).
        float rp[NT] = {0.f, 0.f, 0.f, 0.f};
        #pragma unroll
        for (int mt = 0; mt < CNT; ++mt)
            #pragma unroll
            for (int nt = 0; nt < NT; ++nt)
                #pragma unroll
                for (int r = 0; r < 4; ++r)
                    rp[nt] += __builtin_amdgcn_exp2f(acc[mt][nt][r]);
        #pragma unroll
        for (int nt = 0; nt < NT; ++nt) {
            float v = rp[nt];
            v += __shfl_xor(v, 16, 64);
            v += __shfl_xor(v, 32, 64);
            if (lane < 16) atomicAdd(&rs[rbase + nt * 16 + lane], v);
        }
    }
}

// ---- Phase 2: variable-width stripe GEMM + fused exp-reduction ----
// 80 KiB LDS + <=128 arch-VGPR/wave -> 2 blocks/CU; atomic target sliced by
// (bid & 63) so same-line atomics stop clogging the in-order vmcnt queue.
__global__ __launch_bounds__(512, 4) void adms_main(
    const float* __restrict__ W, const uint4* __restrict__ xnp, float* __restrict__ row_sum)
{
    extern __shared__ uint4 sW[];    // 64-80 KiB, A-fragment-packed W stripe (bf16)
    const int tid = threadIdx.x, bid = blockIdx.x;
    const int tbase = bid * BASE_MT + (bid < EXTRA_T ? bid : EXTRA_T);
    const int cnt   = BASE_MT + (bid < EXTRA_T ? 1 : 0);   // m-tiles this block: 4 or 5
    const int c0 = tbase * 16;

    // Stage W stripe fp32->bf16 into LDS in A-fragment order (no OOB possible).
    for (int g = tid >> 6; g < cnt * KS; g += 8) {
        const int mt = g >> 4, ks = g & 15;
        const int j8 = tid & 3, lm = (tid >> 2) & 15;
        const int gc = c0 + mt * 16 + lm;
        const int k0 = ks * 32 + j8 * 8;
        const float4* src = (const float4*)(W + (size_t)gc * D_DIM + k0);
        sW[(mt * KS + ks) * 64 + (lm | (j8 << 4))] = pack_bf16x8(src[0], src[1]);
    }
    __syncthreads();

    const int w = tid >> 6, lane = tid & 63;
    float* rs = row_sum + (size_t)(bid & (RS_SLICES - 1)) * N_ROWS;
    if (cnt == 5) run_stripe<5>(xnp, sW, rs, w, lane);
    else          run_stripe<4>(xnp, sW, rs, w, lane);
}

// ---- Phase 3: per-row loss (summing the 64 row_sum slices) + mean ----
__global__ __launch_bounds__(1024) void finalize(
    const float* __restrict__ target, const float* __restrict__ row_sum,
    float* __restrict__ out)
{
    __shared__ float red[1024];
    const int t = threadIdx.x;
    float accum = 0.f;
    for (int r = t; r < N_ROWS; r += 1024) {
        float excl_sum = 0.f;
        #pragma unroll 8
        for (int s = 0; s < RS_SLICES; ++s)
            excl_sum += row_sum[s * N_ROWS + r];       // coalesced across t
        const float tg   = target[r];
        const float num  = S_SCALE * (tg - MARGIN);
        const float excl = excl_sum - expf(S_SCALE * tg);
        const float den  = expf(num) + excl;
        accum += num - logf(den);
    }
    red[t] = accum;
    __syncthreads();
    for (int s = 512; s > 0; s >>= 1) {
        if (t < s) red[t] += red[t + s];
        __syncthreads();
    }
    if (t == 0) out[0] = -red[0] / (float)N_ROWS;
}

extern "C" void kernel_launch(void* const* d_in, const int* in_sizes, int n_in,
                              void* d_out, int out_size, void* d_ws, size_t ws_size,
                              hipStream_t stream) {
    const float* x      = (const float*)d_in[0];
    const int*   labels = (const int*)d_in[1];
    const float* W      = (const float*)d_in[2];
    float* out = (float*)d_out;

    char* ws = (char*)d_ws;
    uint4* xnp     = (uint4*)ws;                                   // 4 MiB packed xn
    float* target  = (float*)(ws + (4u << 20));                    // 16 KiB
    float* row_sum = (float*)(ws + (4u << 20) + (16u << 10));      // 64 slices = 1 MiB

    hipFuncSetAttribute((const void*)adms_main,
                        hipFuncAttributeMaxDynamicSharedMemorySize, LDS_BYTES);

    normalize_pack<<<N_ROWS / 4, 256, 0, stream>>>(x, labels, W, xnp, target, row_sum);
    adms_main<<<NBLK, 512, LDS_BYTES, stream>>>(W, xnp, row_sum);
    finalize<<<1, 1024, 0, stream>>>(target, row_sum, out);
}